// Round 1
// baseline (520.595 us; speedup 1.0000x reference)
//
#include <hip/hip_runtime.h>
#include <math.h>

#define DD 1024          // D (in == out features)
#define BT 8192          // B*N tokens
#define TWO_PI 6.28318530717958647692f

// ---------------------------------------------------------------------------
// Kernel 1: T[o][d] = sum_k W[k][o] * e^{-2pi i k d / D}
// One block per column o. Compact the (sparse, ~10) nonzeros of W[:,o] into
// LDS deterministically (per-thread counts + serial prefix), then each thread
// computes 4 d-outputs via a 1024-entry twiddle table.
// ---------------------------------------------------------------------------
__global__ __launch_bounds__(256) void build_T_kernel(
    const float* __restrict__ Wr, const float* __restrict__ Wi,
    float2* __restrict__ T) {
  __shared__ float2 tw[DD];
  __shared__ int    kidx[DD];
  __shared__ float2 wval[DD];
  __shared__ int    offs[257];

  const int o   = blockIdx.x;
  const int tid = threadIdx.x;

  for (int j = tid; j < DD; j += 256) {
    float s, c;
    sincosf((TWO_PI / DD) * (float)j, &s, &c);
    tw[j] = make_float2(c, s);
  }

  // pass 1: count nonzeros in this thread's strided range
  int cnt = 0;
  for (int k = tid; k < DD; k += 256) {
    float wr = Wr[k * DD + o];
    float wi = Wi[k * DD + o];
    if (wr != 0.f || wi != 0.f) cnt++;
  }
  offs[tid + 1] = cnt;
  __syncthreads();
  if (tid == 0) {
    offs[0] = 0;
    for (int i = 1; i <= 256; i++) offs[i] += offs[i - 1];
  }
  __syncthreads();

  // pass 2: deterministic compaction at this thread's offset
  int p = offs[tid];
  for (int k = tid; k < DD; k += 256) {
    float wr = Wr[k * DD + o];
    float wi = Wi[k * DD + o];
    if (wr != 0.f || wi != 0.f) {
      kidx[p] = k;
      wval[p] = make_float2(wr, wi);
      p++;
    }
  }
  __syncthreads();

  const int nnz = offs[256];
  for (int d = tid; d < DD; d += 256) {
    float re = 0.f, im = 0.f;
    for (int j = 0; j < nnz; j++) {
      int    k  = kidx[j];
      float2 w  = wval[j];
      float2 cs = tw[(k * d) & (DD - 1)];
      // W * e^{-i th} = (wr*c + wi*s) + i(wi*c - wr*s)
      re += w.x * cs.x + w.y * cs.y;
      im += w.y * cs.x - w.x * cs.y;
    }
    T[o * DD + d] = make_float2(re, im);
  }
}

// ---------------------------------------------------------------------------
// Kernel 2: M[m][d] = (1/D) * sum_o ( cos(2pi m o/D)*ReT[o][d]
//                                   - sin(2pi m o/D)*ImT[o][d] )
// GEMM-shaped with the "A matrix" generated from the twiddle table via the
// incremental index idx_{o+1} = (idx_o + m) & 1023.
// Block tile 64(m) x 64(d), thread tile 4x4, K-chunk 32 of T staged in LDS.
// ---------------------------------------------------------------------------
#define KC2 32
__global__ __launch_bounds__(256) void build_M_kernel(
    const float2* __restrict__ T, float* __restrict__ M) {
  __shared__ float2 tw[DD];
  __shared__ float2 Ts[KC2][64];

  const int tid = threadIdx.x;
  const int tx  = tid & 15;     // d direction (x4)
  const int ty  = tid >> 4;     // m direction (x4)
  const int m0  = blockIdx.y * 64;
  const int d0  = blockIdx.x * 64;

  for (int j = tid; j < DD; j += 256) {
    float s, c;
    sincosf((TWO_PI / DD) * (float)j, &s, &c);
    tw[j] = make_float2(c, s);
  }

  float acc[4][4] = {};
  int m_[4], idx[4];
#pragma unroll
  for (int i = 0; i < 4; i++) { m_[i] = m0 + ty * 4 + i; idx[i] = 0; }

  for (int oc = 0; oc < DD; oc += KC2) {
    __syncthreads();
    for (int q = tid; q < KC2 * 64; q += 256) {
      int rr = q >> 6, cc = q & 63;
      Ts[rr][cc] = T[(oc + rr) * DD + d0 + cc];
    }
    __syncthreads();
#pragma unroll 8
    for (int ol = 0; ol < KC2; ol++) {
      float2 cs[4];
#pragma unroll
      for (int i = 0; i < 4; i++) {
        cs[i] = tw[idx[i]];
        idx[i] = (idx[i] + m_[i]) & (DD - 1);
      }
      const float4* tsrow = (const float4*)&Ts[ol][0];
      float4 p0 = tsrow[tx * 2];       // (Re t0, Im t0, Re t1, Im t1)
      float4 p1 = tsrow[tx * 2 + 1];   // (Re t2, Im t2, Re t3, Im t3)
      float tr[4] = {p0.x, p0.z, p1.x, p1.z};
      float ti[4] = {p0.y, p0.w, p1.y, p1.w};
#pragma unroll
      for (int i = 0; i < 4; i++)
#pragma unroll
        for (int j = 0; j < 4; j++)
          acc[i][j] += cs[i].x * tr[j] - cs[i].y * ti[j];
    }
  }

  const float inv = 1.0f / (float)DD;
#pragma unroll
  for (int i = 0; i < 4; i++) {
    float4 v = make_float4(acc[i][0] * inv, acc[i][1] * inv,
                           acc[i][2] * inv, acc[i][3] * inv);
    *(float4*)&M[m_[i] * DD + d0 + tx * 4] = v;
  }
}

// ---------------------------------------------------------------------------
// Kernel 3: Y[t][m] = sum_d X[t][d] * M[m][d] + bias[m]   (NT SGEMM)
// Block tile 64(t) x 64(m), thread tile 4x4, K-chunk 32, transposed LDS
// tiles (As[kk][t], Bs[kk][m], padded stride 68) so fragments read as float4.
// ---------------------------------------------------------------------------
#define KC3 32
#define LDP 68
__global__ __launch_bounds__(256) void gemm_y_kernel(
    const float* __restrict__ X, const float* __restrict__ M,
    const float* __restrict__ bias, float* __restrict__ Y) {
  __shared__ float As[KC3][LDP];
  __shared__ float Bs[KC3][LDP];

  const int tid = threadIdx.x;
  const int tx  = tid & 15;     // m direction (x4)
  const int ty  = tid >> 4;     // t direction (x4)
  const int m0  = blockIdx.x * 64;
  const int t0  = blockIdx.y * 64;

  float acc[4][4] = {};

  for (int dc = 0; dc < DD; dc += KC3) {
    __syncthreads();
    // stage 64 rows x 32 k of X and M, transposed into LDS
    for (int q = tid; q < 64 * KC3; q += 256) {
      int r = q >> 5;         // row within tile (t or m)
      int c = q & 31;         // k within chunk
      As[c][r] = X[(t0 + r) * DD + dc + c];
      Bs[c][r] = M[(m0 + r) * DD + dc + c];
    }
    __syncthreads();
#pragma unroll 8
    for (int kk = 0; kk < KC3; kk++) {
      float4 a = *(const float4*)&As[kk][ty * 4];
      float4 b = *(const float4*)&Bs[kk][tx * 4];
      float av[4] = {a.x, a.y, a.z, a.w};
      float bv[4] = {b.x, b.y, b.z, b.w};
#pragma unroll
      for (int i = 0; i < 4; i++)
#pragma unroll
        for (int j = 0; j < 4; j++)
          acc[i][j] += av[i] * bv[j];
    }
  }

  const int mb = m0 + tx * 4;
  float4 bv = *(const float4*)&bias[mb];
#pragma unroll
  for (int i = 0; i < 4; i++) {
    int t = t0 + ty * 4 + i;
    float4 v = make_float4(acc[i][0] + bv.x, acc[i][1] + bv.y,
                           acc[i][2] + bv.z, acc[i][3] + bv.w);
    *(float4*)&Y[t * DD + mb] = v;
  }
}

// ---------------------------------------------------------------------------
extern "C" void kernel_launch(void* const* d_in, const int* in_sizes, int n_in,
                              void* d_out, int out_size, void* d_ws, size_t ws_size,
                              hipStream_t stream) {
  const float* x    = (const float*)d_in[0];   // (B,N,D) = (4,2048,1024) fp32
  const float* wr   = (const float*)d_in[1];   // (D,D) fp32
  const float* wi   = (const float*)d_in[2];   // (D,D) fp32
  const float* bias = (const float*)d_in[3];   // (D,) fp32
  float*       y    = (float*)d_out;           // (B,N,D) fp32

  float2* T = (float2*)d_ws;                              // 8 MB
  float*  M = (float*)((char*)d_ws + (size_t)DD * DD * 8); // 4 MB

  build_T_kernel<<<DD, 256, 0, stream>>>(wr, wi, T);
  build_M_kernel<<<dim3(DD / 64, DD / 64), 256, 0, stream>>>(T, M);
  gemm_y_kernel<<<dim3(DD / 64, BT / 64), 256, 0, stream>>>(x, M, bias, y);
}

// Round 2
// 111.185 us; speedup vs baseline: 4.6822x; 4.6822x over previous
//
#include <hip/hip_runtime.h>
#include <hip/hip_bf16.h>
#include <math.h>

#define DD 1024          // D (in == out features)
#define BT 8192          // B*N tokens
#define TWO_PI 6.28318530717958647692f

typedef float f32x4 __attribute__((ext_vector_type(4)));
typedef short bf16x8 __attribute__((ext_vector_type(8)));
typedef unsigned short u16x8 __attribute__((ext_vector_type(8)));
typedef const __attribute__((address_space(1))) void g_void;
typedef __attribute__((address_space(3))) void l_void;

__device__ __forceinline__ unsigned short f2bf(float f) {
  unsigned int u = __float_as_uint(f);
  unsigned int r = (u + 0x7FFFu + ((u >> 16) & 1u)) >> 16;   // RNE
  return (unsigned short)r;
}

// ---------------------------------------------------------------------------
// Transpose W (Wr,Wi fp32 (k,o)) -> Wt float2 (o,k), coalesced both sides.
// ---------------------------------------------------------------------------
__global__ __launch_bounds__(256) void transpose_W_kernel(
    const float* __restrict__ Wr, const float* __restrict__ Wi,
    float2* __restrict__ Wt) {
  __shared__ float tr[64][65];
  __shared__ float ti[64][65];
  const int k0 = blockIdx.y * 64, o0 = blockIdx.x * 64;
  for (int q = threadIdx.x; q < 64 * 64; q += 256) {
    int r = q >> 6, c = q & 63;                 // r: k, c: o
    tr[r][c] = Wr[(size_t)(k0 + r) * DD + o0 + c];
    ti[r][c] = Wi[(size_t)(k0 + r) * DD + o0 + c];
  }
  __syncthreads();
  for (int q = threadIdx.x; q < 64 * 64; q += 256) {
    int r = q >> 6, c = q & 63;                 // r: o, c: k
    Wt[(size_t)(o0 + r) * DD + k0 + c] = make_float2(tr[c][r], ti[c][r]);
  }
}

// ---------------------------------------------------------------------------
// T[o][d] = sum_k W[k][o] e^{-2pi i k d/D}. One block per o; compact nonzeros
// of row Wt[o][:] (coalesced) into LDS, then 1024-entry twiddle table.
// ---------------------------------------------------------------------------
__global__ __launch_bounds__(256) void build_T_kernel(
    const float2* __restrict__ Wt, float2* __restrict__ T) {
  __shared__ float2 tw[DD];
  __shared__ int    kidx[DD];
  __shared__ float2 wval[DD];
  __shared__ int    offs[257];
  const int o = blockIdx.x, tid = threadIdx.x;

  for (int j = tid; j < DD; j += 256) {
    float s, c;
    sincosf((TWO_PI / DD) * (float)j, &s, &c);
    tw[j] = make_float2(c, s);
  }
  int cnt = 0;
  for (int k = tid; k < DD; k += 256) {
    float2 w = Wt[(size_t)o * DD + k];
    if (w.x != 0.f || w.y != 0.f) cnt++;
  }
  offs[tid + 1] = cnt;
  __syncthreads();
  if (tid == 0) {
    offs[0] = 0;
    for (int i = 1; i <= 256; i++) offs[i] += offs[i - 1];
  }
  __syncthreads();
  int p = offs[tid];
  for (int k = tid; k < DD; k += 256) {
    float2 w = Wt[(size_t)o * DD + k];
    if (w.x != 0.f || w.y != 0.f) { kidx[p] = k; wval[p] = w; p++; }
  }
  __syncthreads();
  const int nnz = offs[256];
  for (int d = tid; d < DD; d += 256) {
    float re = 0.f, im = 0.f;
    for (int j = 0; j < nnz; j++) {
      int    k  = kidx[j];
      float2 w  = wval[j];
      float2 cs = tw[(k * d) & (DD - 1)];
      re += w.x * cs.x + w.y * cs.y;          // W * e^{-i th}
      im += w.y * cs.x - w.x * cs.y;
    }
    T[(size_t)o * DD + d] = make_float2(re, im);
  }
}

// ---------------------------------------------------------------------------
// TT[d][o] = bf16(Re T[o][d]); TT[d][1024+o] = bf16(Im T[o][d])  (transpose)
// ---------------------------------------------------------------------------
__global__ __launch_bounds__(256) void transpose_T_kernel(
    const float2* __restrict__ T, unsigned short* __restrict__ TT) {
  __shared__ float2 tile[64][65];
  const int o0 = blockIdx.x * 64, d0 = blockIdx.y * 64;
  for (int q = threadIdx.x; q < 64 * 64; q += 256) {
    int r = q >> 6, c = q & 63;                 // r: o, c: d
    tile[r][c] = T[(size_t)(o0 + r) * DD + d0 + c];
  }
  __syncthreads();
  for (int q = threadIdx.x; q < 64 * 64; q += 256) {
    int r = q >> 6, c = q & 63;                 // r: d, c: o
    float2 v = tile[c][r];
    TT[(size_t)(d0 + r) * 2048 + o0 + c]        = f2bf(v.x);
    TT[(size_t)(d0 + r) * 2048 + 1024 + o0 + c] = f2bf(v.y);
  }
}

// ---------------------------------------------------------------------------
// CS[m][o] = bf16(cos(2pi m o/D)); CS[m][1024+o] = bf16(-sin(2pi m o/D))
// ---------------------------------------------------------------------------
__global__ __launch_bounds__(256) void gen_CS_kernel(unsigned short* __restrict__ CS) {
  int idx = blockIdx.x * 256 + threadIdx.x;     // 1M = 1024x1024
  int m = idx >> 10, o = idx & 1023;
  float s, c;
  sincosf((TWO_PI / DD) * (float)((m * o) & (DD - 1)), &s, &c);
  CS[(size_t)m * 2048 + o]        = f2bf(c);
  CS[(size_t)m * 2048 + 1024 + o] = f2bf(-s);
}

// ---------------------------------------------------------------------------
// x fp32 -> bf16 (8 elems/thread)
// ---------------------------------------------------------------------------
__global__ __launch_bounds__(256) void convert_x_kernel(
    const float* __restrict__ X, unsigned short* __restrict__ Xb) {
  size_t i = (size_t)blockIdx.x * 256 + threadIdx.x;   // chunk of 8
  const float4* p = (const float4*)(X + i * 8);
  float4 a = p[0], b = p[1];
  u16x8 v;
  v[0] = f2bf(a.x); v[1] = f2bf(a.y); v[2] = f2bf(a.z); v[3] = f2bf(a.w);
  v[4] = f2bf(b.x); v[5] = f2bf(b.y); v[6] = f2bf(b.z); v[7] = f2bf(b.w);
  *(u16x8*)(Xb + i * 8) = v;
}

// ---------------------------------------------------------------------------
// NT bf16 MFMA GEMM (m97 structure): Out[r][c] = scale*sum_k A[r][k]*B[c][k]
// (+bias[c]). 128x128 tile, 4 waves (2x2), 4x4 frags of 16x16x32, BK=32,
// global_load_lds width 16.
// ---------------------------------------------------------------------------
template <int K, bool BIAS, bool OUT_BF16>
__global__ __launch_bounds__(256) void mfma_nt_kernel(
    const unsigned short* __restrict__ A,   // (rows x K) bf16
    const unsigned short* __restrict__ B,   // (cols x K) bf16
    const float* __restrict__ bias,
    void* __restrict__ Out, float scale, int ldo) {
  __shared__ __align__(16) unsigned short Asm[128 * 32];
  __shared__ __align__(16) unsigned short Bsm[128 * 32];
  const int tid  = threadIdx.x;
  const int wave = tid >> 6, lane = tid & 63;
  const int wr = wave >> 1, wc = wave & 1;
  const int row0 = blockIdx.y * 128;
  const int col0 = blockIdx.x * 128;

  f32x4 acc[4][4] = {};

  for (int k0 = 0; k0 < K; k0 += 32) {
    __syncthreads();
#pragma unroll
    for (int is = 0; is < 2; is++) {
      int e = is * 256 + tid;
      int r = e >> 2, c = (e & 3) * 8;
      const unsigned short* ga = A + (size_t)(row0 + r) * K + k0 + c;
      const unsigned short* gb = B + (size_t)(col0 + r) * K + k0 + c;
      __builtin_amdgcn_global_load_lds((g_void*)ga, (l_void*)(Asm + is * 2048 + wave * 512), 16, 0, 0);
      __builtin_amdgcn_global_load_lds((g_void*)gb, (l_void*)(Bsm + is * 2048 + wave * 512), 16, 0, 0);
    }
    __syncthreads();

    bf16x8 af[4], bfr[4];
#pragma unroll
    for (int i = 0; i < 4; i++) {
      int ra = wr * 64 + i * 16 + (lane & 15);
      af[i]  = *(const bf16x8*)&Asm[ra * 32 + (lane >> 4) * 8];
      int rb = wc * 64 + i * 16 + (lane & 15);
      bfr[i] = *(const bf16x8*)&Bsm[rb * 32 + (lane >> 4) * 8];
    }
#pragma unroll
    for (int i = 0; i < 4; i++)
#pragma unroll
      for (int j = 0; j < 4; j++)
        acc[i][j] = __builtin_amdgcn_mfma_f32_16x16x32_bf16(af[i], bfr[j], acc[i][j], 0, 0, 0);
  }

  const int crow0 = row0 + wr * 64;
  const int ccol0 = col0 + wc * 64;
  if (OUT_BF16) {
    unsigned short* O = (unsigned short*)Out;
#pragma unroll
    for (int i = 0; i < 4; i++)
#pragma unroll
      for (int j = 0; j < 4; j++) {
        int cc = ccol0 + j * 16 + (lane & 15);
#pragma unroll
        for (int v = 0; v < 4; v++) {
          int rr = crow0 + i * 16 + (lane >> 4) * 4 + v;
          O[(size_t)rr * ldo + cc] = f2bf(acc[i][j][v] * scale);
        }
      }
  } else {
    float* O = (float*)Out;
    float bv[4];
#pragma unroll
    for (int j = 0; j < 4; j++)
      bv[j] = BIAS ? bias[ccol0 + j * 16 + (lane & 15)] : 0.f;
#pragma unroll
    for (int i = 0; i < 4; i++)
#pragma unroll
      for (int j = 0; j < 4; j++) {
        int cc = ccol0 + j * 16 + (lane & 15);
#pragma unroll
        for (int v = 0; v < 4; v++) {
          int rr = crow0 + i * 16 + (lane >> 4) * 4 + v;
          O[(size_t)rr * ldo + cc] = acc[i][j][v] * scale + bv[j];
        }
      }
  }
}

// ---------------------------------------------------------------------------
extern "C" void kernel_launch(void* const* d_in, const int* in_sizes, int n_in,
                              void* d_out, int out_size, void* d_ws, size_t ws_size,
                              hipStream_t stream) {
  const float* x    = (const float*)d_in[0];
  const float* wrp  = (const float*)d_in[1];
  const float* wip  = (const float*)d_in[2];
  const float* bias = (const float*)d_in[3];
  float*       y    = (float*)d_out;

  char* ws = (char*)d_ws;
  const size_t MB = 1024 * 1024;
  float2*         Wt = (float2*)(ws + 0);           // 8 MB (dead after build_T)
  float2*         T  = (float2*)(ws + 8  * MB);     // 8 MB (dead after transpose_T)
  unsigned short* TT = (unsigned short*)(ws + 16 * MB);  // 4 MB  [d][2048]
  unsigned short* CS = (unsigned short*)(ws + 20 * MB);  // 4 MB  [m][2048]
  unsigned short* Mb = (unsigned short*)(ws + 24 * MB);  // 2 MB  [m][d]
  unsigned short* Xb = (unsigned short*)(ws + 0);        // 16 MB (reuses Wt/T)

  transpose_W_kernel<<<dim3(16, 16), 256, 0, stream>>>(wrp, wip, Wt);
  build_T_kernel<<<DD, 256, 0, stream>>>(Wt, T);
  transpose_T_kernel<<<dim3(16, 16), 256, 0, stream>>>(T, TT);
  gen_CS_kernel<<<4096, 256, 0, stream>>>(CS);
  // M = (1/D) * CS(1024x2048) . TT(1024x2048)^T  -> bf16 (m,d)
  mfma_nt_kernel<2048, false, true><<<dim3(8, 8), 256, 0, stream>>>(
      CS, TT, nullptr, Mb, 1.0f / DD, DD);
  convert_x_kernel<<<4096, 256, 0, stream>>>(x, Xb);
  // Y = Xb(8192x1024) . Mb(1024x1024)^T + bias -> fp32
  mfma_nt_kernel<1024, true, false><<<dim3(8, 64), 256, 0, stream>>>(
      Xb, Mb, bias, y, 1.0f, DD);
}

// Round 3
// 99.483 us; speedup vs baseline: 5.2330x; 1.1176x over previous
//
#include <hip/hip_runtime.h>
#include <hip/hip_bf16.h>
#include <math.h>

#define DD 1024          // D (in == out features)
#define BT 8192          // B*N tokens
#define TWO_PI 6.28318530717958647692f

typedef float f32x4 __attribute__((ext_vector_type(4)));
typedef short bf16x8 __attribute__((ext_vector_type(8)));
typedef unsigned short u16x8 __attribute__((ext_vector_type(8)));
typedef unsigned short u16x4 __attribute__((ext_vector_type(4)));
typedef const __attribute__((address_space(1))) void g_void;
typedef __attribute__((address_space(3))) void l_void;

__device__ __forceinline__ unsigned short f2bf(float f) {
  unsigned int u = __float_as_uint(f);
  unsigned int r = (u + 0x7FFFu + ((u >> 16) & 1u)) >> 16;   // RNE
  return (unsigned short)r;
}

// ---------------------------------------------------------------------------
// Transpose W (Wr,Wi fp32 (k,o)) -> Wt float2 (o,k), coalesced both sides.
// ---------------------------------------------------------------------------
__global__ __launch_bounds__(256) void transpose_W_kernel(
    const float* __restrict__ Wr, const float* __restrict__ Wi,
    float2* __restrict__ Wt) {
  __shared__ float tr[64][65];
  __shared__ float ti[64][65];
  const int k0 = blockIdx.y * 64, o0 = blockIdx.x * 64;
  for (int q = threadIdx.x; q < 64 * 64; q += 256) {
    int r = q >> 6, c = q & 63;                 // r: k, c: o
    tr[r][c] = Wr[(size_t)(k0 + r) * DD + o0 + c];
    ti[r][c] = Wi[(size_t)(k0 + r) * DD + o0 + c];
  }
  __syncthreads();
  for (int q = threadIdx.x; q < 64 * 64; q += 256) {
    int r = q >> 6, c = q & 63;                 // r: o, c: k
    Wt[(size_t)(o0 + r) * DD + k0 + c] = make_float2(tr[c][r], ti[c][r]);
  }
}

// ---------------------------------------------------------------------------
// T[o][d] = sum_k W[k][o] e^{-2pi i k d/D}. One block per o; compact nonzeros
// of row Wt[o][:] (coalesced) into LDS, then 1024-entry twiddle table.
// ---------------------------------------------------------------------------
__global__ __launch_bounds__(256) void build_T_kernel(
    const float2* __restrict__ Wt, float2* __restrict__ T) {
  __shared__ float2 tw[DD];
  __shared__ int    kidx[DD];
  __shared__ float2 wval[DD];
  __shared__ int    offs[257];
  const int o = blockIdx.x, tid = threadIdx.x;

  for (int j = tid; j < DD; j += 256) {
    float s, c;
    sincosf((TWO_PI / DD) * (float)j, &s, &c);
    tw[j] = make_float2(c, s);
  }
  int cnt = 0;
  for (int k = tid; k < DD; k += 256) {
    float2 w = Wt[(size_t)o * DD + k];
    if (w.x != 0.f || w.y != 0.f) cnt++;
  }
  offs[tid + 1] = cnt;
  __syncthreads();
  if (tid == 0) {
    offs[0] = 0;
    for (int i = 1; i <= 256; i++) offs[i] += offs[i - 1];
  }
  __syncthreads();
  int p = offs[tid];
  for (int k = tid; k < DD; k += 256) {
    float2 w = Wt[(size_t)o * DD + k];
    if (w.x != 0.f || w.y != 0.f) { kidx[p] = k; wval[p] = w; p++; }
  }
  __syncthreads();
  const int nnz = offs[256];
  for (int d = tid; d < DD; d += 256) {
    float re = 0.f, im = 0.f;
    for (int j = 0; j < nnz; j++) {
      int    k  = kidx[j];
      float2 w  = wval[j];
      float2 cs = tw[(k * d) & (DD - 1)];
      re += w.x * cs.x + w.y * cs.y;          // W * e^{-i th}
      im += w.y * cs.x - w.x * cs.y;
    }
    T[(size_t)o * DD + d] = make_float2(re, im);
  }
}

// ---------------------------------------------------------------------------
// TT[d][o] = bf16(Re T[o][d]); TT[d][1024+o] = bf16(Im T[o][d])  (transpose)
// ---------------------------------------------------------------------------
__global__ __launch_bounds__(256) void transpose_T_kernel(
    const float2* __restrict__ T, unsigned short* __restrict__ TT) {
  __shared__ float2 tile[64][65];
  const int o0 = blockIdx.x * 64, d0 = blockIdx.y * 64;
  for (int q = threadIdx.x; q < 64 * 64; q += 256) {
    int r = q >> 6, c = q & 63;                 // r: o, c: d
    tile[r][c] = T[(size_t)(o0 + r) * DD + d0 + c];
  }
  __syncthreads();
  for (int q = threadIdx.x; q < 64 * 64; q += 256) {
    int r = q >> 6, c = q & 63;                 // r: d, c: o
    float2 v = tile[c][r];
    TT[(size_t)(d0 + r) * 2048 + o0 + c]        = f2bf(v.x);
    TT[(size_t)(d0 + r) * 2048 + 1024 + o0 + c] = f2bf(v.y);
  }
}

// ---------------------------------------------------------------------------
// CS[m][o] = bf16(cos(2pi m o/D)); CS[m][1024+o] = bf16(-sin(2pi m o/D))
// ---------------------------------------------------------------------------
__global__ __launch_bounds__(256) void gen_CS_kernel(unsigned short* __restrict__ CS) {
  int idx = blockIdx.x * 256 + threadIdx.x;     // 1M = 1024x1024
  int m = idx >> 10, o = idx & 1023;
  float s, c;
  sincosf((TWO_PI / DD) * (float)((m * o) & (DD - 1)), &s, &c);
  CS[(size_t)m * 2048 + o]        = f2bf(c);
  CS[(size_t)m * 2048 + 1024 + o] = f2bf(-s);
}

// ---------------------------------------------------------------------------
// x fp32 -> bf16 (8 elems/thread)
// ---------------------------------------------------------------------------
__global__ __launch_bounds__(256) void convert_x_kernel(
    const float* __restrict__ X, unsigned short* __restrict__ Xb) {
  size_t i = (size_t)blockIdx.x * 256 + threadIdx.x;   // chunk of 8
  const float4* p = (const float4*)(X + i * 8);
  float4 a = p[0], b = p[1];
  u16x8 v;
  v[0] = f2bf(a.x); v[1] = f2bf(a.y); v[2] = f2bf(a.z); v[3] = f2bf(a.w);
  v[4] = f2bf(b.x); v[5] = f2bf(b.y); v[6] = f2bf(b.z); v[7] = f2bf(b.w);
  *(u16x8*)(Xb + i * 8) = v;
}

// ---------------------------------------------------------------------------
// NT bf16 MFMA GEMM (m97 structure): Out[r][c] = sum_k A[r][k]*B[c][k]
// 128x128 tile, 4 waves (2x2), 4x4 frags of 16x16x32, BK=32,
// global_load_lds width 16. K-range = [blockIdx.z*kLen, +kLen).
// MODE 0: fp32 out, *scale + bias[c].  MODE 2: fp32 partial out at
//         Out + blockIdx.z*DD*DD (no scale/bias).
// ---------------------------------------------------------------------------
template <int LDK, int MODE>
__global__ __launch_bounds__(256) void mfma_nt_kernel(
    const unsigned short* __restrict__ A,   // (rows x LDK) bf16
    const unsigned short* __restrict__ B,   // (cols x LDK) bf16
    const float* __restrict__ bias,
    float* __restrict__ Out, float scale, int ldo, int kLen) {
  __shared__ __align__(16) unsigned short Asm[128 * 32];
  __shared__ __align__(16) unsigned short Bsm[128 * 32];
  const int tid  = threadIdx.x;
  const int wave = tid >> 6, lane = tid & 63;
  const int wr = wave >> 1, wc = wave & 1;
  const int row0 = blockIdx.y * 128;
  const int col0 = blockIdx.x * 128;
  const int kBeg = blockIdx.z * kLen;

  f32x4 acc[4][4] = {};

  for (int k0 = kBeg; k0 < kBeg + kLen; k0 += 32) {
    __syncthreads();
#pragma unroll
    for (int is = 0; is < 2; is++) {
      int e = is * 256 + tid;
      int r = e >> 2, c = (e & 3) * 8;
      const unsigned short* ga = A + (size_t)(row0 + r) * LDK + k0 + c;
      const unsigned short* gb = B + (size_t)(col0 + r) * LDK + k0 + c;
      __builtin_amdgcn_global_load_lds((g_void*)ga, (l_void*)(Asm + is * 2048 + wave * 512), 16, 0, 0);
      __builtin_amdgcn_global_load_lds((g_void*)gb, (l_void*)(Bsm + is * 2048 + wave * 512), 16, 0, 0);
    }
    __syncthreads();

    bf16x8 af[4], bfr[4];
#pragma unroll
    for (int i = 0; i < 4; i++) {
      int ra = wr * 64 + i * 16 + (lane & 15);
      af[i]  = *(const bf16x8*)&Asm[ra * 32 + (lane >> 4) * 8];
      int rb = wc * 64 + i * 16 + (lane & 15);
      bfr[i] = *(const bf16x8*)&Bsm[rb * 32 + (lane >> 4) * 8];
    }
#pragma unroll
    for (int i = 0; i < 4; i++)
#pragma unroll
      for (int j = 0; j < 4; j++)
        acc[i][j] = __builtin_amdgcn_mfma_f32_16x16x32_bf16(af[i], bfr[j], acc[i][j], 0, 0, 0);
  }

  const int crow0 = row0 + wr * 64;
  const int ccol0 = col0 + wc * 64;
  if (MODE == 2) {
    float* O = Out + (size_t)blockIdx.z * DD * DD;
#pragma unroll
    for (int i = 0; i < 4; i++)
#pragma unroll
      for (int j = 0; j < 4; j++) {
        int cc = ccol0 + j * 16 + (lane & 15);
#pragma unroll
        for (int v = 0; v < 4; v++) {
          int rr = crow0 + i * 16 + (lane >> 4) * 4 + v;
          O[(size_t)rr * ldo + cc] = acc[i][j][v];
        }
      }
  } else {
    float bv[4];
#pragma unroll
    for (int j = 0; j < 4; j++)
      bv[j] = bias[ccol0 + j * 16 + (lane & 15)];
#pragma unroll
    for (int i = 0; i < 4; i++)
#pragma unroll
      for (int j = 0; j < 4; j++) {
        int cc = ccol0 + j * 16 + (lane & 15);
#pragma unroll
        for (int v = 0; v < 4; v++) {
          int rr = crow0 + i * 16 + (lane >> 4) * 4 + v;
          Out[(size_t)rr * ldo + cc] = acc[i][j][v] * scale + bv[j];
        }
      }
  }
}

// ---------------------------------------------------------------------------
// Mb[i] = bf16( (P0[i]+P1[i]+P2[i]+P3[i]) / D ),  i over 1M elements, x4 vec.
// ---------------------------------------------------------------------------
__global__ __launch_bounds__(256) void reduce_M_kernel(
    const float* __restrict__ P, unsigned short* __restrict__ Mb) {
  const size_t NE = (size_t)DD * DD;
  size_t i = ((size_t)blockIdx.x * 256 + threadIdx.x) * 4;
  float4 s = *(const float4*)(P + i);
#pragma unroll
  for (int z = 1; z < 4; z++) {
    float4 p = *(const float4*)(P + z * NE + i);
    s.x += p.x; s.y += p.y; s.z += p.z; s.w += p.w;
  }
  const float inv = 1.0f / (float)DD;
  u16x4 v;
  v[0] = f2bf(s.x * inv); v[1] = f2bf(s.y * inv);
  v[2] = f2bf(s.z * inv); v[3] = f2bf(s.w * inv);
  *(u16x4*)(Mb + i) = v;
}

// ---------------------------------------------------------------------------
extern "C" void kernel_launch(void* const* d_in, const int* in_sizes, int n_in,
                              void* d_out, int out_size, void* d_ws, size_t ws_size,
                              hipStream_t stream) {
  const float* x    = (const float*)d_in[0];
  const float* wrp  = (const float*)d_in[1];
  const float* wip  = (const float*)d_in[2];
  const float* bias = (const float*)d_in[3];
  float*       y    = (float*)d_out;

  char* ws = (char*)d_ws;
  const size_t MB = 1024 * 1024;
  // Region 0..16MB is time-shared: Wt (dead after build_T), T at 8..16MB
  // (dead after transpose_T), then P partials, then Xb.
  float2*         Wt = (float2*)(ws + 0);                // 8 MB
  float2*         T  = (float2*)(ws + 8  * MB);          // 8 MB
  unsigned short* TT = (unsigned short*)(ws + 16 * MB);  // 4 MB  [d][2048]
  unsigned short* CS = (unsigned short*)(ws + 20 * MB);  // 4 MB  [m][2048]
  unsigned short* Mb = (unsigned short*)(ws + 24 * MB);  // 2 MB  [m][d]
  float*          P  = (float*)(ws + 0);                 // 16 MB partials
  unsigned short* Xb = (unsigned short*)(ws + 0);        // 16 MB (after reduce)

  transpose_W_kernel<<<dim3(16, 16), 256, 0, stream>>>(wrp, wip, Wt);
  build_T_kernel<<<DD, 256, 0, stream>>>(Wt, T);
  transpose_T_kernel<<<dim3(16, 16), 256, 0, stream>>>(T, TT);
  gen_CS_kernel<<<4096, 256, 0, stream>>>(CS);
  // P[z] = CS(1024x2048) . TT^T over K-chunk z of 512   (split-K x4)
  mfma_nt_kernel<2048, 2><<<dim3(8, 8, 4), 256, 0, stream>>>(
      CS, TT, nullptr, P, 1.0f, DD, 512);
  reduce_M_kernel<<<DD * DD / (256 * 4), 256, 0, stream>>>(P, Mb);
  convert_x_kernel<<<4096, 256, 0, stream>>>(x, Xb);
  // Y = Xb(8192x1024) . Mb(1024x1024)^T + bias -> fp32
  mfma_nt_kernel<1024, 0><<<dim3(8, 64, 1), 256, 0, stream>>>(
      Xb, Mb, bias, y, 1.0f, DD, 1024);
}